// Round 12
// baseline (460.740 us; speedup 1.0000x reference)
//
#include <hip/hip_runtime.h>

#define N_NODES   50000
#define N_EDGES   600000
#define F         128
#define N_GRAPHS  512
#define MROWS     32          // rows per block in layer kernel
#define ASTRIDE   264         // Ahi LDS row stride in shorts (16B-aligned)
#define ALSTRIDE  136         // Alo LDS row stride in shorts (agg half only)
#define NB_SCAN   196         // ceil(N_NODES/256)
#define EB        16          // edge batch depth (concurrent gathers/thread)

typedef short          short8   __attribute__((ext_vector_type(8)));
typedef float          f32x4    __attribute__((ext_vector_type(4)));
typedef unsigned int   uint4_t  __attribute__((ext_vector_type(4)));

__device__ __forceinline__ void split_bf16(float v, short& hi, short& lo) {
    unsigned u  = __float_as_uint(v);
    unsigned hb = u & 0xFFFF0000u;
    hi = (short)(u >> 16);
    float rem = v - __uint_as_float(hb);
    lo = (short)(__float_as_uint(rem) >> 16);
}

// f32 -> bf16 round-to-nearest-even
__device__ __forceinline__ unsigned short f2bf_rne(float f) {
    unsigned u = __float_as_uint(f);
    u += 0x7FFFu + ((u >> 16) & 1u);
    return (unsigned short)(u >> 16);
}

// ---------------------------------------------------------------------------
// prepA: x->bf16, W transpose+split, degree histogram, zero-row init.
// deg must be pre-zeroed (memset).
__global__ __launch_bounds__(256) void prepA_kernel(
    const float* __restrict__ x, unsigned short* __restrict__ xb,
    unsigned short* __restrict__ hb0, unsigned short* __restrict__ hb1,
    const float* __restrict__ Wl0, const float* __restrict__ Wr0,
    const float* __restrict__ Wl1, const float* __restrict__ Wr1,
    const float* __restrict__ Wl2, const float* __restrict__ Wr2,
    const float* __restrict__ Wl3, const float* __restrict__ Wr3,
    short* __restrict__ wtbase,
    const int* __restrict__ dst, int* __restrict__ deg)
{
    const int gid  = blockIdx.x * 256 + threadIdx.x;
    const int nthr = gridDim.x * 256;

    // zero row N_NODES of the three h buffers (gather padding target)
    if (gid < 48) {
        int bsel = gid >> 4, c = gid & 15;
        unsigned short* p = (bsel == 0 ? xb : bsel == 1 ? hb0 : hb1)
                            + (size_t)N_NODES * F + c * 8;
        short8 z = {0,0,0,0,0,0,0,0};
        *(short8*)p = z;
    }

    // x -> bf16 (8 elems per iteration)
    for (int i = gid; i < (N_NODES * F) / 8; i += nthr) {
        float4 a = ((const float4*)x)[2 * i];
        float4 b = ((const float4*)x)[2 * i + 1];
        short8 o;
        o[0] = (short)f2bf_rne(a.x); o[1] = (short)f2bf_rne(a.y);
        o[2] = (short)f2bf_rne(a.z); o[3] = (short)f2bf_rne(a.w);
        o[4] = (short)f2bf_rne(b.x); o[5] = (short)f2bf_rne(b.y);
        o[6] = (short)f2bf_rne(b.z); o[7] = (short)f2bf_rne(b.w);
        ((short8*)xb)[i] = o;
    }

    // W split: gt = l*32768 + n*256 + k
    for (int gt = gid; gt < 131072; gt += nthr) {
        int l = gt >> 15;
        int t = gt & 32767;
        const float* Wl; const float* Wr;
        switch (l) {
            case 0:  Wl = Wl0; Wr = Wr0; break;
            case 1:  Wl = Wl1; Wr = Wr1; break;
            case 2:  Wl = Wl2; Wr = Wr2; break;
            default: Wl = Wl3; Wr = Wr3; break;
        }
        int n = t >> 8, k = t & 255;
        float w = (k < F) ? Wl[k * F + n] : Wr[(k - F) * F + n];
        short h, lo;
        split_bf16(w, h, lo);
        short* hi_plane = wtbase + (size_t)l * 65536;
        hi_plane[t]         = h;
        hi_plane[32768 + t] = lo;
    }

    // degree histogram
    for (int e = gid; e < N_EDGES; e += nthr) atomicAdd(&deg[dst[e]], 1);
}

// ---- per-block sums of deg ----
__global__ __launch_bounds__(256) void bsum_kernel(const int* __restrict__ deg,
                                                   int* __restrict__ bsum) {
    int i = blockIdx.x * 256 + threadIdx.x;
    int v = (i < N_NODES) ? deg[i] : 0;
    #pragma unroll
    for (int off = 32; off > 0; off >>= 1) v += __shfl_down(v, off, 64);
    __shared__ int wsum[4];
    if ((threadIdx.x & 63) == 0) wsum[threadIdx.x >> 6] = v;
    __syncthreads();
    if (threadIdx.x == 0) bsum[blockIdx.x] = wsum[0] + wsum[1] + wsum[2] + wsum[3];
}

// ---- scan+apply: every block redundantly scans the 196 block sums ----
__global__ __launch_bounds__(256) void scan_apply_kernel(
    const int* __restrict__ deg, const int* __restrict__ bsum,
    int* __restrict__ row_start, int* __restrict__ cursor,
    float* __restrict__ inv_deg)
{
    __shared__ int s[256];
    const int b = blockIdx.x, t = threadIdx.x;

    int v = (t < NB_SCAN) ? bsum[t] : 0;
    s[t] = v;
    __syncthreads();
    for (int off = 1; off < 256; off <<= 1) {
        int xv  = s[t];
        int add = (t >= off) ? s[t - off] : 0;
        __syncthreads();
        s[t] = xv + add;
        __syncthreads();
    }
    const int boff = (b == 0) ? 0 : s[b - 1];
    __syncthreads();

    int i = b * 256 + t;
    int d = (i < N_NODES) ? deg[i] : 0;
    s[t] = d;
    __syncthreads();
    for (int off = 1; off < 256; off <<= 1) {
        int xv  = s[t];
        int add = (t >= off) ? s[t - off] : 0;
        __syncthreads();
        s[t] = xv + add;
        __syncthreads();
    }
    int excl = s[t] - d + boff;
    if (i < N_NODES) {
        row_start[i] = excl;
        cursor[i]    = excl;
        inv_deg[i]   = 1.0f / fmaxf((float)d, 1.0f);
    }
    if (b == 0 && t == 0) row_start[N_NODES] = N_EDGES;
}

__global__ void fill_kernel(const int* __restrict__ src, const int* __restrict__ dst,
                            int* __restrict__ cursor, int* __restrict__ eidx) {
    int e = blockIdx.x * blockDim.x + threadIdx.x;
    if (e < N_EDGES) {
        int p = atomicAdd(&cursor[dst[e]], 1);
        eidx[p] = src[e];
    }
}

// ---------------------------------------------------------------------------
// Fused layer (bf16 h): gather-mean (f32 accum) -> split-bf16 MFMA -> relu.
// Padded gather slots target the zero row (N_NODES) -> no mask math.
__global__ __launch_bounds__(512) void layer_kernel(
    const unsigned short* __restrict__ hb_in, const int* __restrict__ row_start,
    const int* __restrict__ eidx, const float* __restrict__ inv_deg,
    const short* __restrict__ wt_hi, const short* __restrict__ wt_lo,
    const float* __restrict__ b, unsigned short* __restrict__ hb_out)
{
    __shared__ short Ahi[MROWS][ASTRIDE];
    __shared__ short Alo[MROWS][ALSTRIDE];   // agg half only

    const int t    = threadIdx.x;
    const int base = blockIdx.x * MROWS;

    // ---- gather phase: thread = (row rr, 8-col group c8) ----
    {
        const int c8  = t & 15;
        const int rr  = t >> 4;          // 0..31
        const int row = base + rr;
        const bool v  = (row < N_NODES);

        int a0 = 0, na = 0;
        float sc = 0.0f;
        if (v) {
            a0 = row_start[row];
            na = row_start[row + 1] - a0;
            sc = inv_deg[row];
        }

        short8 selfv = {0,0,0,0,0,0,0,0};
        if (v) selfv = *(const short8*)(hb_in + (size_t)row * F + c8 * 8);

        float acc[8] = {0,0,0,0,0,0,0,0};
        for (int eo = 0; eo < na; eo += EB) {
            int idx[EB];
            #pragma unroll
            for (int u = 0; u < EB; ++u) {
                bool ok = (eo + u) < na;
                int  sl = ok ? a0 + eo + u : a0;
                int  ia = eidx[sl];
                idx[u] = ok ? ia : N_NODES;   // zero row
            }
            #pragma unroll
            for (int u = 0; u < EB; ++u) {
                short8 hv = *(const short8*)(hb_in + (size_t)idx[u] * F + c8 * 8);
                uint4_t uw = *(const uint4_t*)&hv;
                #pragma unroll
                for (int q = 0; q < 4; ++q) {
                    unsigned wq = uw[q];
                    acc[2 * q]     += __uint_as_float(wq << 16);
                    acc[2 * q + 1] += __uint_as_float(wq & 0xFFFF0000u);
                }
            }
        }

        short8 h8, l8;
        #pragma unroll
        for (int k = 0; k < 8; ++k) {
            short h, l;
            split_bf16(acc[k] * sc, h, l);
            h8[k] = h; l8[k] = l;
        }
        *(short8*)&Ahi[rr][c8 * 8] = h8;
        *(short8*)&Alo[rr][c8 * 8] = l8;
        *(short8*)&Ahi[rr][F + c8 * 8] = selfv;
    }
    __syncthreads();

    // ---- MFMA phase: wave w owns cols [w*16, w*16+16) ----
    const int w    = t >> 6;         // 0..7
    const int lane = t & 63;
    const int m    = lane & 15;
    const int quad = lane >> 4;
    const int n0   = w * 16 + m;

    f32x4 acc0 = {0,0,0,0};          // rows 0..15
    f32x4 acc1 = {0,0,0,0};          // rows 16..31

    #pragma unroll
    for (int ks = 0; ks < 4; ++ks) {             // agg half: hi + lo planes
        const int ko = ks * 32 + quad * 8;
        short8 ah0 = *(const short8*)&Ahi[m][ko];
        short8 ah1 = *(const short8*)&Ahi[16 + m][ko];
        short8 al0 = *(const short8*)&Alo[m][ko];
        short8 al1 = *(const short8*)&Alo[16 + m][ko];
        short8 bh  = *(const short8*)&wt_hi[(size_t)n0 * 256 + ko];
        short8 bl  = *(const short8*)&wt_lo[(size_t)n0 * 256 + ko];

        acc0 = __builtin_amdgcn_mfma_f32_16x16x32_bf16(ah0, bh, acc0, 0, 0, 0);
        acc0 = __builtin_amdgcn_mfma_f32_16x16x32_bf16(ah0, bl, acc0, 0, 0, 0);
        acc0 = __builtin_amdgcn_mfma_f32_16x16x32_bf16(al0, bh, acc0, 0, 0, 0);

        acc1 = __builtin_amdgcn_mfma_f32_16x16x32_bf16(ah1, bh, acc1, 0, 0, 0);
        acc1 = __builtin_amdgcn_mfma_f32_16x16x32_bf16(ah1, bl, acc1, 0, 0, 0);
        acc1 = __builtin_amdgcn_mfma_f32_16x16x32_bf16(al1, bh, acc1, 0, 0, 0);
    }
    #pragma unroll
    for (int ks = 4; ks < 8; ++ks) {             // self half: lo plane of A == 0
        const int ko = ks * 32 + quad * 8;
        short8 ah0 = *(const short8*)&Ahi[m][ko];
        short8 ah1 = *(const short8*)&Ahi[16 + m][ko];
        short8 bh  = *(const short8*)&wt_hi[(size_t)n0 * 256 + ko];
        short8 bl  = *(const short8*)&wt_lo[(size_t)n0 * 256 + ko];

        acc0 = __builtin_amdgcn_mfma_f32_16x16x32_bf16(ah0, bh, acc0, 0, 0, 0);
        acc0 = __builtin_amdgcn_mfma_f32_16x16x32_bf16(ah0, bl, acc0, 0, 0, 0);

        acc1 = __builtin_amdgcn_mfma_f32_16x16x32_bf16(ah1, bh, acc1, 0, 0, 0);
        acc1 = __builtin_amdgcn_mfma_f32_16x16x32_bf16(ah1, bl, acc1, 0, 0, 0);
    }

    // ---- epilogue: C/D layout col=lane&15, row=quad*4+reg ----
    float bj = b[n0];
    #pragma unroll
    for (int reg = 0; reg < 4; ++reg) {
        int r0 = base + quad * 4 + reg;
        int r1 = r0 + 16;
        if (r0 < N_NODES)
            hb_out[(size_t)r0 * F + n0] = f2bf_rne(fmaxf(acc0[reg] + bj, 0.0f));
        if (r1 < N_NODES)
            hb_out[(size_t)r1 * F + n0] = f2bf_rne(fmaxf(acc1[reg] + bj, 0.0f));
    }
}

// ---------------------------------------------------------------------------
// Fused pool+head, 512 threads: 4 row-groups x 128 cols, LDS reductions.
__global__ __launch_bounds__(512) void poolhead_kernel(
    const int* __restrict__ batch, const unsigned short* __restrict__ hb,
    const float* __restrict__ Wf1, const float* __restrict__ bf1,
    const float* __restrict__ Wf2, const float* __restrict__ bf2,
    float* __restrict__ out)
{
    const int g   = blockIdx.x;
    const int j   = threadIdx.x & 127;
    const int grp = threadIdx.x >> 7;    // 0..3

    int lo = 0, hi = N_NODES;
    while (lo < hi) { int m = (lo + hi) >> 1; if (batch[m] < g) lo = m + 1; else hi = m; }
    int start = lo;
    hi = N_NODES;
    while (lo < hi) { int m = (lo + hi) >> 1; if (batch[m] <= g) lo = m + 1; else hi = m; }
    int end = lo;

    float acc = 0.0f;
    for (int r = start + grp; r < end; r += 4)
        acc += __uint_as_float((unsigned)hb[(size_t)r * F + j] << 16);

    __shared__ float part[4][F];
    __shared__ float p[F];
    __shared__ float emb[F];
    part[grp][j] = acc;
    __syncthreads();
    if (grp == 0) {
        float tot = (part[0][j] + part[1][j]) + (part[2][j] + part[3][j]);
        p[j] = tot / fmaxf((float)(end - start), 1.0f);
    }
    __syncthreads();

    // 128->128 MLP: k-range split across groups
    float e = 0.0f;
    #pragma unroll 8
    for (int k = grp * 32; k < grp * 32 + 32; ++k) e += p[k] * Wf1[k * F + j];
    part[grp][j] = e;
    __syncthreads();
    if (grp == 0)
        emb[j] = (part[0][j] + part[1][j]) + (part[2][j] + part[3][j]) + bf1[j];
    __syncthreads();

    if (threadIdx.x < 2) {
        float o = bf2[threadIdx.x];
        for (int k = 0; k < F; ++k) o += emb[k] * Wf2[k * 2 + threadIdx.x];
        out[(size_t)g * 2 + threadIdx.x] = o;
    }
}

extern "C" void kernel_launch(void* const* d_in, const int* in_sizes, int n_in,
                              void* d_out, int out_size, void* d_ws, size_t ws_size,
                              hipStream_t stream) {
    const float* x     = (const float*)d_in[0];
    const int*   ei    = (const int*)d_in[1];
    const int*   src   = ei;
    const int*   dst   = ei + N_EDGES;
    const int*   batch = (const int*)d_in[2];
    const float* Wl0 = (const float*)d_in[4];
    const float* Wr0 = (const float*)d_in[5];
    const float* Wl1 = (const float*)d_in[7];
    const float* Wr1 = (const float*)d_in[8];
    const float* Wl2 = (const float*)d_in[10];
    const float* Wr2 = (const float*)d_in[11];
    const float* Wl3 = (const float*)d_in[13];
    const float* Wr3 = (const float*)d_in[14];
    const float* bb[4] = {(const float*)d_in[6],  (const float*)d_in[9],
                          (const float*)d_in[12], (const float*)d_in[15]};
    const float* Wf1 = (const float*)d_in[16];
    const float* bf1 = (const float*)d_in[17];
    const float* Wf2 = (const float*)d_in[18];
    const float* bf2 = (const float*)d_in[19];
    float* out = (float*)d_out;

    // workspace layout (h buffers have one extra zero row at index N_NODES)
    const size_t HSZ = (size_t)(N_NODES + 1) * F;      // incl. zero row
    unsigned short* XB  = (unsigned short*)d_ws;       // bf16 x
    unsigned short* HB0 = XB + HSZ;
    unsigned short* HB1 = HB0 + HSZ;
    float* inv_deg   = (float*)(HB1 + HSZ);            // N_NODES
    int*   row_start = (int*)(inv_deg + N_NODES);      // N_NODES+1
    int*   cursor    = row_start + N_NODES + 1;        // N_NODES
    int*   eidx      = cursor + N_NODES;               // N_EDGES
    int*   deg_i     = eidx + N_EDGES;                 // N_NODES (zeroed)
    int*   bsum      = deg_i + N_NODES;                // 256
    short* wtbase    = (short*)(bsum + 256);           // 4 x 65536 shorts

    (void)hipMemsetAsync(deg_i, 0, N_NODES * sizeof(int), stream);

    // CSR build + weight prep + x conversion
    prepA_kernel<<<1024, 256, 0, stream>>>(
        x, XB, HB0, HB1, Wl0, Wr0, Wl1, Wr1, Wl2, Wr2, Wl3, Wr3,
        wtbase, dst, deg_i);
    bsum_kernel<<<NB_SCAN, 256, 0, stream>>>(deg_i, bsum);
    scan_apply_kernel<<<NB_SCAN, 256, 0, stream>>>(deg_i, bsum, row_start, cursor, inv_deg);
    fill_kernel<<<(N_EDGES + 255) / 256, 256, 0, stream>>>(src, dst, cursor, eidx);

    const int layer_blocks = (N_NODES + MROWS - 1) / MROWS;  // 1563
    const unsigned short* hin = XB;
    unsigned short* buf[2] = {HB0, HB1};
    for (int l = 0; l < 4; ++l) {
        unsigned short* tgt = buf[l & 1];
        const short* whi = wtbase + (size_t)l * 65536;
        const short* wlo = whi + 32768;
        layer_kernel<<<layer_blocks, 512, 0, stream>>>(
            hin, row_start, eidx, inv_deg, whi, wlo, bb[l], tgt);
        hin = tgt;
    }

    poolhead_kernel<<<N_GRAPHS, 512, 0, stream>>>(batch, hin, Wf1, bf1, Wf2, bf2, out);
}

// Round 13
// 401.404 us; speedup vs baseline: 1.1478x; 1.1478x over previous
//
#include <hip/hip_runtime.h>

#define N_NODES   50000
#define N_EDGES   600000
#define F         128
#define N_GRAPHS  512
#define MROWS     32          // rows per block in layer kernel
#define ASTRIDE   264         // Ahi LDS row stride in shorts (16B-aligned)
#define ALSTRIDE  136         // Alo LDS row stride in shorts (agg half only)
#define NB_SCAN   196         // ceil(N_NODES/256)
#define EB        8           // edge batch depth (8x short8 = 32 dest VGPRs, fits)

typedef short          short8   __attribute__((ext_vector_type(8)));
typedef float          f32x4    __attribute__((ext_vector_type(4)));
typedef unsigned int   uint4_t  __attribute__((ext_vector_type(4)));

__device__ __forceinline__ void split_bf16(float v, short& hi, short& lo) {
    unsigned u  = __float_as_uint(v);
    unsigned hb = u & 0xFFFF0000u;
    hi = (short)(u >> 16);
    float rem = v - __uint_as_float(hb);
    lo = (short)(__float_as_uint(rem) >> 16);
}

// f32 -> bf16 round-to-nearest-even
__device__ __forceinline__ unsigned short f2bf_rne(float f) {
    unsigned u = __float_as_uint(f);
    u += 0x7FFFu + ((u >> 16) & 1u);
    return (unsigned short)(u >> 16);
}

// ---------------------------------------------------------------------------
// prepA: x->bf16, W transpose+split, degree histogram, zero-row init.
// deg must be pre-zeroed (memset).
__global__ __launch_bounds__(256) void prepA_kernel(
    const float* __restrict__ x, unsigned short* __restrict__ xb,
    unsigned short* __restrict__ hb0, unsigned short* __restrict__ hb1,
    const float* __restrict__ Wl0, const float* __restrict__ Wr0,
    const float* __restrict__ Wl1, const float* __restrict__ Wr1,
    const float* __restrict__ Wl2, const float* __restrict__ Wr2,
    const float* __restrict__ Wl3, const float* __restrict__ Wr3,
    short* __restrict__ wtbase,
    const int* __restrict__ dst, int* __restrict__ deg)
{
    const int gid  = blockIdx.x * 256 + threadIdx.x;
    const int nthr = gridDim.x * 256;

    // zero row N_NODES of the three h buffers (gather padding target)
    if (gid < 48) {
        int bsel = gid >> 4, c = gid & 15;
        unsigned short* p = (bsel == 0 ? xb : bsel == 1 ? hb0 : hb1)
                            + (size_t)N_NODES * F + c * 8;
        short8 z = {0,0,0,0,0,0,0,0};
        *(short8*)p = z;
    }

    // x -> bf16 (8 elems per iteration)
    for (int i = gid; i < (N_NODES * F) / 8; i += nthr) {
        float4 a = ((const float4*)x)[2 * i];
        float4 b = ((const float4*)x)[2 * i + 1];
        short8 o;
        o[0] = (short)f2bf_rne(a.x); o[1] = (short)f2bf_rne(a.y);
        o[2] = (short)f2bf_rne(a.z); o[3] = (short)f2bf_rne(a.w);
        o[4] = (short)f2bf_rne(b.x); o[5] = (short)f2bf_rne(b.y);
        o[6] = (short)f2bf_rne(b.z); o[7] = (short)f2bf_rne(b.w);
        ((short8*)xb)[i] = o;
    }

    // W split: gt = l*32768 + n*256 + k
    for (int gt = gid; gt < 131072; gt += nthr) {
        int l = gt >> 15;
        int t = gt & 32767;
        const float* Wl; const float* Wr;
        switch (l) {
            case 0:  Wl = Wl0; Wr = Wr0; break;
            case 1:  Wl = Wl1; Wr = Wr1; break;
            case 2:  Wl = Wl2; Wr = Wr2; break;
            default: Wl = Wl3; Wr = Wr3; break;
        }
        int n = t >> 8, k = t & 255;
        float w = (k < F) ? Wl[k * F + n] : Wr[(k - F) * F + n];
        short h, lo;
        split_bf16(w, h, lo);
        short* hi_plane = wtbase + (size_t)l * 65536;
        hi_plane[t]         = h;
        hi_plane[32768 + t] = lo;
    }

    // degree histogram
    for (int e = gid; e < N_EDGES; e += nthr) atomicAdd(&deg[dst[e]], 1);
}

// ---- per-block sums of deg ----
__global__ __launch_bounds__(256) void bsum_kernel(const int* __restrict__ deg,
                                                   int* __restrict__ bsum) {
    int i = blockIdx.x * 256 + threadIdx.x;
    int v = (i < N_NODES) ? deg[i] : 0;
    #pragma unroll
    for (int off = 32; off > 0; off >>= 1) v += __shfl_down(v, off, 64);
    __shared__ int wsum[4];
    if ((threadIdx.x & 63) == 0) wsum[threadIdx.x >> 6] = v;
    __syncthreads();
    if (threadIdx.x == 0) bsum[blockIdx.x] = wsum[0] + wsum[1] + wsum[2] + wsum[3];
}

// ---- scan+apply: every block redundantly scans the 196 block sums ----
__global__ __launch_bounds__(256) void scan_apply_kernel(
    const int* __restrict__ deg, const int* __restrict__ bsum,
    int* __restrict__ row_start, int* __restrict__ cursor,
    float* __restrict__ inv_deg)
{
    __shared__ int s[256];
    const int b = blockIdx.x, t = threadIdx.x;

    int v = (t < NB_SCAN) ? bsum[t] : 0;
    s[t] = v;
    __syncthreads();
    for (int off = 1; off < 256; off <<= 1) {
        int xv  = s[t];
        int add = (t >= off) ? s[t - off] : 0;
        __syncthreads();
        s[t] = xv + add;
        __syncthreads();
    }
    const int boff = (b == 0) ? 0 : s[b - 1];
    __syncthreads();

    int i = b * 256 + t;
    int d = (i < N_NODES) ? deg[i] : 0;
    s[t] = d;
    __syncthreads();
    for (int off = 1; off < 256; off <<= 1) {
        int xv  = s[t];
        int add = (t >= off) ? s[t - off] : 0;
        __syncthreads();
        s[t] = xv + add;
        __syncthreads();
    }
    int excl = s[t] - d + boff;
    if (i < N_NODES) {
        row_start[i] = excl;
        cursor[i]    = excl;
        inv_deg[i]   = 1.0f / fmaxf((float)d, 1.0f);
    }
    if (b == 0 && t == 0) row_start[N_NODES] = N_EDGES;
}

__global__ void fill_kernel(const int* __restrict__ src, const int* __restrict__ dst,
                            int* __restrict__ cursor, int* __restrict__ eidx) {
    int e = blockIdx.x * blockDim.x + threadIdx.x;
    if (e < N_EDGES) {
        int p = atomicAdd(&cursor[dst[e]], 1);
        eidx[p] = src[e];
    }
}

// ---------------------------------------------------------------------------
// Fused layer (bf16 h): gather-mean (f32 accum) -> split-bf16 MFMA -> relu.
// Padded gather slots target the zero row (N_NODES) -> no mask math.
__global__ __launch_bounds__(512) void layer_kernel(
    const unsigned short* __restrict__ hb_in, const int* __restrict__ row_start,
    const int* __restrict__ eidx, const float* __restrict__ inv_deg,
    const short* __restrict__ wt_hi, const short* __restrict__ wt_lo,
    const float* __restrict__ b, unsigned short* __restrict__ hb_out)
{
    __shared__ short Ahi[MROWS][ASTRIDE];
    __shared__ short Alo[MROWS][ALSTRIDE];   // agg half only

    const int t    = threadIdx.x;
    const int base = blockIdx.x * MROWS;

    // ---- gather phase: thread = (row rr, 8-col group c8) ----
    {
        const int c8  = t & 15;
        const int rr  = t >> 4;          // 0..31
        const int row = base + rr;
        const bool v  = (row < N_NODES);

        int a0 = 0, na = 0;
        float sc = 0.0f;
        if (v) {
            a0 = row_start[row];
            na = row_start[row + 1] - a0;
            sc = inv_deg[row];
        }

        short8 selfv = {0,0,0,0,0,0,0,0};
        if (v) selfv = *(const short8*)(hb_in + (size_t)row * F + c8 * 8);

        float acc[8] = {0,0,0,0,0,0,0,0};
        for (int eo = 0; eo < na; eo += EB) {
            int idx[EB];
            #pragma unroll
            for (int u = 0; u < EB; ++u) {
                bool ok = (eo + u) < na;
                int  sl = ok ? a0 + eo + u : a0;
                int  ia = eidx[sl];
                idx[u] = ok ? ia : N_NODES;   // zero row
            }
            #pragma unroll
            for (int u = 0; u < EB; ++u) {
                short8 hv = *(const short8*)(hb_in + (size_t)idx[u] * F + c8 * 8);
                uint4_t uw = *(const uint4_t*)&hv;
                #pragma unroll
                for (int q = 0; q < 4; ++q) {
                    unsigned wq = uw[q];
                    acc[2 * q]     += __uint_as_float(wq << 16);
                    acc[2 * q + 1] += __uint_as_float(wq & 0xFFFF0000u);
                }
            }
        }

        short8 h8, l8;
        #pragma unroll
        for (int k = 0; k < 8; ++k) {
            short h, l;
            split_bf16(acc[k] * sc, h, l);
            h8[k] = h; l8[k] = l;
        }
        *(short8*)&Ahi[rr][c8 * 8] = h8;
        *(short8*)&Alo[rr][c8 * 8] = l8;
        *(short8*)&Ahi[rr][F + c8 * 8] = selfv;
    }
    __syncthreads();

    // ---- MFMA phase: wave w owns cols [w*16, w*16+16) ----
    const int w    = t >> 6;         // 0..7
    const int lane = t & 63;
    const int m    = lane & 15;
    const int quad = lane >> 4;
    const int n0   = w * 16 + m;

    f32x4 acc0 = {0,0,0,0};          // rows 0..15
    f32x4 acc1 = {0,0,0,0};          // rows 16..31

    #pragma unroll
    for (int ks = 0; ks < 4; ++ks) {             // agg half: hi + lo planes
        const int ko = ks * 32 + quad * 8;
        short8 ah0 = *(const short8*)&Ahi[m][ko];
        short8 ah1 = *(const short8*)&Ahi[16 + m][ko];
        short8 al0 = *(const short8*)&Alo[m][ko];
        short8 al1 = *(const short8*)&Alo[16 + m][ko];
        short8 bh  = *(const short8*)&wt_hi[(size_t)n0 * 256 + ko];
        short8 bl  = *(const short8*)&wt_lo[(size_t)n0 * 256 + ko];

        acc0 = __builtin_amdgcn_mfma_f32_16x16x32_bf16(ah0, bh, acc0, 0, 0, 0);
        acc0 = __builtin_amdgcn_mfma_f32_16x16x32_bf16(ah0, bl, acc0, 0, 0, 0);
        acc0 = __builtin_amdgcn_mfma_f32_16x16x32_bf16(al0, bh, acc0, 0, 0, 0);

        acc1 = __builtin_amdgcn_mfma_f32_16x16x32_bf16(ah1, bh, acc1, 0, 0, 0);
        acc1 = __builtin_amdgcn_mfma_f32_16x16x32_bf16(ah1, bl, acc1, 0, 0, 0);
        acc1 = __builtin_amdgcn_mfma_f32_16x16x32_bf16(al1, bh, acc1, 0, 0, 0);
    }
    #pragma unroll
    for (int ks = 4; ks < 8; ++ks) {             // self half: lo plane of A == 0
        const int ko = ks * 32 + quad * 8;
        short8 ah0 = *(const short8*)&Ahi[m][ko];
        short8 ah1 = *(const short8*)&Ahi[16 + m][ko];
        short8 bh  = *(const short8*)&wt_hi[(size_t)n0 * 256 + ko];
        short8 bl  = *(const short8*)&wt_lo[(size_t)n0 * 256 + ko];

        acc0 = __builtin_amdgcn_mfma_f32_16x16x32_bf16(ah0, bh, acc0, 0, 0, 0);
        acc0 = __builtin_amdgcn_mfma_f32_16x16x32_bf16(ah0, bl, acc0, 0, 0, 0);

        acc1 = __builtin_amdgcn_mfma_f32_16x16x32_bf16(ah1, bh, acc1, 0, 0, 0);
        acc1 = __builtin_amdgcn_mfma_f32_16x16x32_bf16(ah1, bl, acc1, 0, 0, 0);
    }

    // ---- epilogue: C/D layout col=lane&15, row=quad*4+reg ----
    float bj = b[n0];
    #pragma unroll
    for (int reg = 0; reg < 4; ++reg) {
        int r0 = base + quad * 4 + reg;
        int r1 = r0 + 16;
        if (r0 < N_NODES)
            hb_out[(size_t)r0 * F + n0] = f2bf_rne(fmaxf(acc0[reg] + bj, 0.0f));
        if (r1 < N_NODES)
            hb_out[(size_t)r1 * F + n0] = f2bf_rne(fmaxf(acc1[reg] + bj, 0.0f));
    }
}

// ---------------------------------------------------------------------------
// Fused pool+head, 512 threads: 4 row-groups x 128 cols, LDS reductions.
__global__ __launch_bounds__(512) void poolhead_kernel(
    const int* __restrict__ batch, const unsigned short* __restrict__ hb,
    const float* __restrict__ Wf1, const float* __restrict__ bf1,
    const float* __restrict__ Wf2, const float* __restrict__ bf2,
    float* __restrict__ out)
{
    const int g   = blockIdx.x;
    const int j   = threadIdx.x & 127;
    const int grp = threadIdx.x >> 7;    // 0..3

    int lo = 0, hi = N_NODES;
    while (lo < hi) { int m = (lo + hi) >> 1; if (batch[m] < g) lo = m + 1; else hi = m; }
    int start = lo;
    hi = N_NODES;
    while (lo < hi) { int m = (lo + hi) >> 1; if (batch[m] <= g) lo = m + 1; else hi = m; }
    int end = lo;

    float acc = 0.0f;
    for (int r = start + grp; r < end; r += 4)
        acc += __uint_as_float((unsigned)hb[(size_t)r * F + j] << 16);

    __shared__ float part[4][F];
    __shared__ float p[F];
    __shared__ float emb[F];
    part[grp][j] = acc;
    __syncthreads();
    if (grp == 0) {
        float tot = (part[0][j] + part[1][j]) + (part[2][j] + part[3][j]);
        p[j] = tot / fmaxf((float)(end - start), 1.0f);
    }
    __syncthreads();

    // 128->128 MLP: k-range split across groups
    float e = 0.0f;
    #pragma unroll 8
    for (int k = grp * 32; k < grp * 32 + 32; ++k) e += p[k] * Wf1[k * F + j];
    part[grp][j] = e;
    __syncthreads();
    if (grp == 0)
        emb[j] = (part[0][j] + part[1][j]) + (part[2][j] + part[3][j]) + bf1[j];
    __syncthreads();

    if (threadIdx.x < 2) {
        float o = bf2[threadIdx.x];
        for (int k = 0; k < F; ++k) o += emb[k] * Wf2[k * 2 + threadIdx.x];
        out[(size_t)g * 2 + threadIdx.x] = o;
    }
}

extern "C" void kernel_launch(void* const* d_in, const int* in_sizes, int n_in,
                              void* d_out, int out_size, void* d_ws, size_t ws_size,
                              hipStream_t stream) {
    const float* x     = (const float*)d_in[0];
    const int*   ei    = (const int*)d_in[1];
    const int*   src   = ei;
    const int*   dst   = ei + N_EDGES;
    const int*   batch = (const int*)d_in[2];
    const float* Wl0 = (const float*)d_in[4];
    const float* Wr0 = (const float*)d_in[5];
    const float* Wl1 = (const float*)d_in[7];
    const float* Wr1 = (const float*)d_in[8];
    const float* Wl2 = (const float*)d_in[10];
    const float* Wr2 = (const float*)d_in[11];
    const float* Wl3 = (const float*)d_in[13];
    const float* Wr3 = (const float*)d_in[14];
    const float* bb[4] = {(const float*)d_in[6],  (const float*)d_in[9],
                          (const float*)d_in[12], (const float*)d_in[15]};
    const float* Wf1 = (const float*)d_in[16];
    const float* bf1 = (const float*)d_in[17];
    const float* Wf2 = (const float*)d_in[18];
    const float* bf2 = (const float*)d_in[19];
    float* out = (float*)d_out;

    // workspace layout (h buffers have one extra zero row at index N_NODES)
    const size_t HSZ = (size_t)(N_NODES + 1) * F;      // incl. zero row
    unsigned short* XB  = (unsigned short*)d_ws;       // bf16 x
    unsigned short* HB0 = XB + HSZ;
    unsigned short* HB1 = HB0 + HSZ;
    float* inv_deg   = (float*)(HB1 + HSZ);            // N_NODES
    int*   row_start = (int*)(inv_deg + N_NODES);      // N_NODES+1
    int*   cursor    = row_start + N_NODES + 1;        // N_NODES
    int*   eidx      = cursor + N_NODES;               // N_EDGES
    int*   deg_i     = eidx + N_EDGES;                 // N_NODES (zeroed)
    int*   bsum      = deg_i + N_NODES;                // 256
    short* wtbase    = (short*)(bsum + 256);           // 4 x 65536 shorts

    (void)hipMemsetAsync(deg_i, 0, N_NODES * sizeof(int), stream);

    // CSR build + weight prep + x conversion
    prepA_kernel<<<1024, 256, 0, stream>>>(
        x, XB, HB0, HB1, Wl0, Wr0, Wl1, Wr1, Wl2, Wr2, Wl3, Wr3,
        wtbase, dst, deg_i);
    bsum_kernel<<<NB_SCAN, 256, 0, stream>>>(deg_i, bsum);
    scan_apply_kernel<<<NB_SCAN, 256, 0, stream>>>(deg_i, bsum, row_start, cursor, inv_deg);
    fill_kernel<<<(N_EDGES + 255) / 256, 256, 0, stream>>>(src, dst, cursor, eidx);

    const int layer_blocks = (N_NODES + MROWS - 1) / MROWS;  // 1563
    const unsigned short* hin = XB;
    unsigned short* buf[2] = {HB0, HB1};
    for (int l = 0; l < 4; ++l) {
        unsigned short* tgt = buf[l & 1];
        const short* whi = wtbase + (size_t)l * 65536;
        const short* wlo = whi + 32768;
        layer_kernel<<<layer_blocks, 512, 0, stream>>>(
            hin, row_start, eidx, inv_deg, whi, wlo, bb[l], tgt);
        hin = tgt;
    }

    poolhead_kernel<<<N_GRAPHS, 512, 0, stream>>>(batch, hin, Wf1, bf1, Wf2, bf2, out);
}